// Round 2
// baseline (170.236 us; speedup 1.0000x reference)
//
#include <hip/hip_runtime.h>
#include <hip/hip_bf16.h>

#define HH 64
#define WW 64
#define S  68          // padded LDS row stride (floats)
#define PH 66          // padded rows (1-px zero frame)
#define NLQ 10
#define NK 40

// One block per image. 512 threads: thread t owns column x = t&63, rows y0..y0+7
// with y0 = (t>>6)*8. q0 (80 f32) and transition weights (90 f32) in registers;
// v ping-pongs between two padded LDS planes (frame stays 0 == conv zero-pad).
// All I/O fp32 (reference declares jnp.float32 everywhere).
__global__ __launch_bounds__(512, 2) void vin_fused(
    const float* __restrict__ X,    // [B,2,64,64]
    const float* __restrict__ Wh,   // [150,2,3,3]
    const float* __restrict__ bh,   // [150]
    const float* __restrict__ Wr,   // [150]  (1x1 conv weight)
    const float* __restrict__ Wq,   // [10,1,3,3]
    const float* __restrict__ wtr,  // [10,1,3,3] transition
    const float* __restrict__ Wc,   // [4096] critic weight
    const float* __restrict__ bc,   // [1]
    float* __restrict__ out)        // [256 critic] ++ [256*40960 q]
{
  __shared__ float vb[2][PH * S];
  __shared__ float rb[PH * S];
  __shared__ float Wef[19];   // collapsed X->r conv weights + bias
  __shared__ float Wqs[90];
  __shared__ float Wts[90];
  __shared__ float red[8];

  const int b  = blockIdx.x;
  const int t  = threadIdx.x;
  const int x  = t & 63;
  const int yg = t >> 6;
  const int y0 = yg << 3;

  // ---- zero LDS (frames must be 0; interiors overwritten) ----
  {
    float* vbf = &vb[0][0];
    for (int i = t; i < 2 * PH * S; i += 512) vbf[i] = 0.f;
    for (int i = t; i < PH * S; i += 512) rb[i] = 0.f;
  }
  __syncthreads();

  // ---- stage X (both channels) into vb interiors; collapse weights ----
  const float* Xb = X + (size_t)b * (2 * HH * WW);
  for (int i = t; i < HH * WW; i += 512) {
    const int yy = i >> 6, xx = i & 63;
    vb[0][(yy + 1) * S + xx + 1] = Xb[i];
    vb[1][(yy + 1) * S + xx + 1] = Xb[HH * WW + i];
  }
  if (t < 19) {
    float s = 0.f;
    if (t < 18) {
      const int ci = t / 9, k = t - ci * 9;
      for (int c = 0; c < 150; ++c)
        s += Wr[c] * Wh[c * 18 + ci * 9 + k];
    } else {
      for (int c = 0; c < 150; ++c) s += Wr[c] * bh[c];
    }
    Wef[t] = s;
  } else if (t < 109) {
    Wqs[t - 19] = Wq[t - 19];
  } else if (t < 199) {
    Wts[t - 109] = wtr[t - 109];
  }
  __syncthreads();

  // ---- r = conv(X, Weff, pad=1) + beff  -> rb ----
  {
    float We[19];
#pragma unroll
    for (int i = 0; i < 19; ++i) We[i] = Wef[i];
#pragma unroll
    for (int j = 0; j < 8; ++j) {
      const int tb = (y0 + j) * S + x;   // top-left of 3x3 patch in padded coords
      float s = We[18];
#pragma unroll
      for (int dy = 0; dy < 3; ++dy)
#pragma unroll
        for (int dx = 0; dx < 3; ++dx) {
          const int idx = tb + dy * S + dx;
          s = fmaf(vb[0][idx], We[dy * 3 + dx], s);
          s = fmaf(vb[1][idx], We[9 + dy * 3 + dx], s);
        }
      rb[tb + S + 1] = s;
    }
  }
  __syncthreads();

  // ---- q0 = conv(r, Wq, pad=1) -> regs; v_init = max_l q0 -> vb[0] ----
  float q0r[8][NLQ];
  {
    float Wqf[90];
#pragma unroll
    for (int i = 0; i < 90; ++i) Wqf[i] = Wqs[i];
#pragma unroll
    for (int j = 0; j < 8; ++j) {
      const int tb = (y0 + j) * S + x;
      float p[9];
#pragma unroll
      for (int dy = 0; dy < 3; ++dy)
#pragma unroll
        for (int dx = 0; dx < 3; ++dx) p[dy * 3 + dx] = rb[tb + dy * S + dx];
      float m = -3.0e38f;
#pragma unroll
      for (int l = 0; l < NLQ; ++l) {
        float s = 0.f;
#pragma unroll
        for (int k = 0; k < 9; ++k) s = fmaf(Wqf[l * 9 + k], p[k], s);
        q0r[j][l] = s;
        m = fmaxf(m, s);
      }
      vb[0][tb + S + 1] = m;
    }
  }
  __syncthreads();

  // ---- K-loop: q_{i+1} = q0 + conv(v_i, w); v = max_ch ----
  float Wt[90];
#pragma unroll
  for (int i = 0; i < 90; ++i) Wt[i] = Wts[i];

  const int base0 = y0 * S + x;

  auto step = [&](const float* __restrict__ vin, float* __restrict__ vout) {
    float a0 = vin[base0],     a1 = vin[base0 + 1],     a2 = vin[base0 + 2];
    float b0 = vin[base0 + S], b1 = vin[base0 + S + 1], b2 = vin[base0 + S + 2];
#pragma unroll
    for (int j = 0; j < 8; ++j) {
      const int rbx = base0 + (j + 2) * S;
      float c0 = vin[rbx], c1 = vin[rbx + 1], c2 = vin[rbx + 2];
      float m = -3.0e38f;
#pragma unroll
      for (int l = 0; l < NLQ; ++l) {
        float s = q0r[j][l];
        s = fmaf(Wt[l * 9 + 0], a0, s);
        s = fmaf(Wt[l * 9 + 1], a1, s);
        s = fmaf(Wt[l * 9 + 2], a2, s);
        s = fmaf(Wt[l * 9 + 3], b0, s);
        s = fmaf(Wt[l * 9 + 4], b1, s);
        s = fmaf(Wt[l * 9 + 5], b2, s);
        s = fmaf(Wt[l * 9 + 6], c0, s);
        s = fmaf(Wt[l * 9 + 7], c1, s);
        s = fmaf(Wt[l * 9 + 8], c2, s);
        m = fmaxf(m, s);
      }
      vout[base0 + (j + 1) * S + 1] = m;
      a0 = b0; a1 = b1; a2 = b2;
      b0 = c0; b1 = c1; b2 = c2;
    }
    __syncthreads();
  };

  // 39 regular iterations (it=0..38), then final (it=39) with stores.
  for (int s2 = 0; s2 < 19; ++s2) { step(vb[0], vb[1]); step(vb[1], vb[0]); }
  step(vb[0], vb[1]);  // it = 38: reads vb[0], writes vb[1]

  // ---- final iteration: emit q_K + accumulate critic dot ----
  float wcv[8];
#pragma unroll
  for (int j = 0; j < 8; ++j) wcv[j] = Wc[(y0 + j) * WW + x];

  float* qo = out + 256 + (size_t)b * (NLQ * HH * WW) + y0 * WW + x;
  float acc = 0.f;
  {
    const float* vin = vb[1];
    float a0 = vin[base0],     a1 = vin[base0 + 1],     a2 = vin[base0 + 2];
    float b0 = vin[base0 + S], b1 = vin[base0 + S + 1], b2 = vin[base0 + S + 2];
#pragma unroll
    for (int j = 0; j < 8; ++j) {
      const int rbx = base0 + (j + 2) * S;
      float c0 = vin[rbx], c1 = vin[rbx + 1], c2 = vin[rbx + 2];
      float m = -3.0e38f;
#pragma unroll
      for (int l = 0; l < NLQ; ++l) {
        float s = q0r[j][l];
        s = fmaf(Wt[l * 9 + 0], a0, s);
        s = fmaf(Wt[l * 9 + 1], a1, s);
        s = fmaf(Wt[l * 9 + 2], a2, s);
        s = fmaf(Wt[l * 9 + 3], b0, s);
        s = fmaf(Wt[l * 9 + 4], b1, s);
        s = fmaf(Wt[l * 9 + 5], b2, s);
        s = fmaf(Wt[l * 9 + 6], c0, s);
        s = fmaf(Wt[l * 9 + 7], c1, s);
        s = fmaf(Wt[l * 9 + 8], c2, s);
        qo[l * (HH * WW) + j * WW] = s;
        m = fmaxf(m, s);
      }
      acc = fmaf(m, wcv[j], acc);
      a0 = b0; a1 = b1; a2 = b2;
      b0 = c0; b1 = c1; b2 = c2;
    }
  }

  // ---- block-reduce critic ----
#pragma unroll
  for (int off = 32; off > 0; off >>= 1) acc += __shfl_down(acc, off);
  if ((t & 63) == 0) red[yg] = acc;
  __syncthreads();
  if (t == 0) {
    float s = bc[0];
#pragma unroll
    for (int i = 0; i < 8; ++i) s += red[i];
    out[b] = s;
  }
}

extern "C" void kernel_launch(void* const* d_in, const int* in_sizes, int n_in,
                              void* d_out, int out_size, void* d_ws, size_t ws_size,
                              hipStream_t stream) {
  (void)n_in; (void)out_size; (void)d_ws; (void)ws_size;
  const float* X   = (const float*)d_in[0];
  const float* Wh  = (const float*)d_in[1];
  const float* bh  = (const float*)d_in[2];
  const float* Wr  = (const float*)d_in[3];
  const float* Wq  = (const float*)d_in[4];
  const float* wtr = (const float*)d_in[5];
  const float* Wc  = (const float*)d_in[6];
  const float* bc  = (const float*)d_in[7];
  float* out = (float*)d_out;

  const int B = in_sizes[0] / (2 * HH * WW);   // 256
  vin_fused<<<B, 512, 0, stream>>>(X, Wh, bh, Wr, Wq, wtr, Wc, bc, out);
}